// Round 5
// baseline (223.558 us; speedup 1.0000x reference)
//
#include <hip/hip_runtime.h>
#include <hip/hip_bf16.h>
#include <math.h>

#define N_NODES 50000
#define N_EDGES 1600000
#define IN_DIM  128
#define HID     64
#define EPB     4096   // edges per sort block
#define NBLK    391    // ceil(N_EDGES / EPB)
#define NB      391    // ceil(N_NODES / 128) buckets of 128 nodes
#define CAP     8192   // LDS staging capacity (edges/bucket; mean 4092)
static constexpr float EPS = 1e-6f;

typedef __attribute__((ext_vector_type(8))) short          short8;   // 8 bf16
typedef __attribute__((ext_vector_type(8))) unsigned short ushort8;
typedef __attribute__((ext_vector_type(4))) unsigned short bf16x4_t;
typedef __attribute__((ext_vector_type(4))) int            i32x4;
typedef __attribute__((ext_vector_type(4))) float          f32x4;
typedef __attribute__((ext_vector_type(2))) float          f32x2;

__device__ __forceinline__ float bf2f(unsigned int hi_bits) {   // bits already in [31:16]
    union { unsigned int i; float f; } c; c.i = hi_bits; return c.f;
}
__device__ __forceinline__ unsigned short f2bf(float f) {   // round-nearest-even
    union { float f; unsigned int i; } c; c.f = f;
    unsigned int r = c.i + 0x7FFFu + ((c.i >> 16) & 1u);
    return (unsigned short)(r >> 16);
}
__device__ __forceinline__ unsigned char f2fp8(float f) {   // OCP e4m3, HW cvt
    int p = __builtin_amdgcn_cvt_pk_fp8_f32(f, f, 0, false);
    return (unsigned char)(p & 0xff);
}

// ==== weight packing =========================================================

template <int K>
__device__ __forceinline__ void pack_body(const float* __restrict__ wS,
                                          const float* __restrict__ wN,
                                          unsigned short* __restrict__ pS,
                                          unsigned short* __restrict__ pN, int blk) {
    constexpr int NSLOT = (K / 32) * 4 * 64;
    int slot = blk * 256 + (int)threadIdx.x;
    if (slot >= NSLOT) return;
    int lane = slot & 63;
    int ct   = slot >> 6;
    int t    = ct & 3;
    int c    = ct >> 2;
    int m    = lane & 15;
    int quad = lane >> 4;
    int col  = t * 16 + m;
#pragma unroll
    for (int j = 0; j < 8; ++j) {
        int k = c * 32 + quad * 8 + j;
        pS[slot * 8 + j] = f2bf(wS[k * 64 + col]);
        pN[slot * 8 + j] = f2bf(wN[k * 64 + col]);
    }
}

// ==== CSR build: binned counting sort ========================================

// blocks 0..NBLK-1: per-block bucket histogram; blocks NBLK..NBLK+7: weight pack
// (also writes the 64B zero row at hnq[N_NODES] used for gather tail-masking)
__global__ __launch_bounds__(256) void bucket_count_pack(
    const int* __restrict__ ei, int* __restrict__ blockCounts,
    const float* __restrict__ w0s, const float* __restrict__ w0n,
    const float* __restrict__ w1s, const float* __restrict__ w1n,
    const float* __restrict__ w2s, const float* __restrict__ w2n,
    unsigned short* __restrict__ p0S, unsigned short* __restrict__ p0N,
    unsigned short* __restrict__ p1S, unsigned short* __restrict__ p1N,
    unsigned short* __restrict__ p2S, unsigned short* __restrict__ p2N,
    unsigned char* __restrict__ hnq) {
    if (blockIdx.x >= NBLK) {
        int blk = blockIdx.x - NBLK;
        if (blk == 7 && threadIdx.x >= 128 && threadIdx.x < 144)
            ((unsigned int*)(hnq + (size_t)N_NODES * HID))[threadIdx.x - 128] = 0u;
        if (blk < 4)      pack_body<IN_DIM>(w0s, w0n, p0S, p0N, blk);
        else if (blk < 6) pack_body<HID>(w1s, w1n, p1S, p1N, blk - 4);
        else              pack_body<HID>(w2s, w2n, p2S, p2N, blk - 6);
        return;
    }
    __shared__ int hist[NB];
    for (int i = threadIdx.x; i < NB; i += 256) hist[i] = 0;
    __syncthreads();
    int base = blockIdx.x * EPB;
    int lim  = min(EPB, N_EDGES - base);
    for (int i = threadIdx.x; i < lim; i += 256)
        atomicAdd(&hist[ei[N_EDGES + base + i] >> 7], 1);
    __syncthreads();
    for (int b = threadIdx.x; b < NB; b += 256)
        blockCounts[blockIdx.x * NB + b] = hist[b];
}

// ==== dual GEMM body =========================================================
// hs = A@wS (fp32 out), hn = A@wN (fp8 e4m3 out)
template <int K, bool F32IN>
__device__ __forceinline__ void gemm_body(
    const void* __restrict__ Av,
    const unsigned short* __restrict__ pS,
    const unsigned short* __restrict__ pN,
    float* __restrict__ hs, unsigned char* __restrict__ hnq, int blk) {
    constexpr int NC = K / 32;
    int lane = threadIdx.x & 63;
    int wv   = threadIdx.x >> 6;
    int tile = blk * 4 + wv;
    if (tile >= N_NODES / 16) return;
    int m    = lane & 15;
    int quad = lane >> 4;

    const short8* pSf = (const short8*)pS;
    const short8* pNf = (const short8*)pN;

    f32x4 accS[4], accN[4];
#pragma unroll
    for (int t = 0; t < 4; ++t) {
        accS[t] = (f32x4){0.f, 0.f, 0.f, 0.f};
        accN[t] = (f32x4){0.f, 0.f, 0.f, 0.f};
    }
#pragma unroll
    for (int c = 0; c < NC; ++c) {
        short8 a;
        if constexpr (F32IN) {
            const float* Af = (const float*)Av + ((size_t)tile * 16 + m) * K + quad * 8 + c * 32;
            f32x4 a0 = *(const f32x4*)Af;
            f32x4 a1 = *(const f32x4*)(Af + 4);
#pragma unroll
            for (int k = 0; k < 4; ++k) a[k]     = (short)f2bf(a0[k]);
#pragma unroll
            for (int k = 0; k < 4; ++k) a[k + 4] = (short)f2bf(a1[k]);
        } else {
            const short8* Af = (const short8*)((const unsigned short*)Av +
                               ((size_t)tile * 16 + m) * K + quad * 8);
            a = Af[c * 4];
        }
#pragma unroll
        for (int t = 0; t < 4; ++t) {
            short8 bs = pSf[(c * 4 + t) * 64 + lane];
            short8 bn = pNf[(c * 4 + t) * 64 + lane];
            accS[t] = __builtin_amdgcn_mfma_f32_16x16x32_bf16(a, bs, accS[t], 0, 0, 0);
            accN[t] = __builtin_amdgcn_mfma_f32_16x16x32_bf16(a, bn, accN[t], 0, 0, 0);
        }
    }
    int row0 = tile * 16 + quad * 4;
#pragma unroll
    for (int t = 0; t < 4; ++t) {
#pragma unroll
        for (int r = 0; r < 4; ++r) {
            size_t o = (size_t)(row0 + r) * HID + t * 16 + m;
            hs[o]  = accS[t][r];
            hnq[o] = f2fp8(accN[t][r]);
        }
    }
}

// blocks 0..NB-1: col_sum; blocks NB.. : layer-0 GEMM (independent work overlap)
__global__ __launch_bounds__(256) void col_sum_gemm0(
    const int* __restrict__ blockCounts, int* __restrict__ totals,
    const float* __restrict__ x,
    const unsigned short* __restrict__ p0S, const unsigned short* __restrict__ p0N,
    float* __restrict__ hs, unsigned char* __restrict__ hnq) {
    if (blockIdx.x >= NB) {
        gemm_body<IN_DIM, true>(x, p0S, p0N, hs, hnq, blockIdx.x - NB);
        return;
    }
    __shared__ int ws[4];
    int b = blockIdx.x;
    int s = 0;
    for (int i = threadIdx.x; i < NBLK; i += 256) s += blockCounts[i * NB + b];
#pragma unroll
    for (int off = 32; off >= 1; off >>= 1) s += __shfl_xor(s, off, 64);
    if ((threadIdx.x & 63) == 0) ws[threadIdx.x >> 6] = s;
    __syncthreads();
    if (threadIdx.x == 0) totals[b] = ws[0] + ws[1] + ws[2] + ws[3];
}

// col_fix + integrated base scan
__global__ __launch_bounds__(256) void col_fix_base(int* __restrict__ blockCounts,
                                                    const int* __restrict__ totals,
                                                    int* __restrict__ bucketBase) {
    __shared__ int vals[NBLK];
    __shared__ int sbase;
    int b = blockIdx.x;
    for (int i = threadIdx.x; i < NBLK; i += 256) vals[i] = blockCounts[i * NB + b];
    if (threadIdx.x < 64) {   // wave 0: base_b = sum totals[0..b)
        int lane = threadIdx.x;
        int s = 0;
        for (int i = lane; i < b; i += 64) s += totals[i];
#pragma unroll
        for (int off = 32; off >= 1; off >>= 1) s += __shfl_xor(s, off, 64);
        if (lane == 0) {
            sbase = s;
            bucketBase[b] = s;
            if (b == NB - 1) bucketBase[NB] = s + totals[b];   // == N_EDGES
        }
    }
    __syncthreads();
    if (threadIdx.x < 64) {
        int lane  = threadIdx.x;
        int carry = sbase;
        for (int base = 0; base < NBLK; base += 64) {
            int i = base + lane;
            int v = (i < NBLK) ? vals[i] : 0;
            int incl = v;
#pragma unroll
            for (int off = 1; off < 64; off <<= 1) {
                int t = __shfl_up(incl, off, 64);
                if (lane >= off) incl += t;
            }
            if (i < NBLK) vals[i] = carry + incl - v;
            carry += __shfl(incl, 63, 64);
        }
    }
    __syncthreads();
    for (int i = threadIdx.x; i < NBLK; i += 256) blockCounts[i * NB + b] = vals[i];
}

// scatter edges into bucket-sorted order, packed (src<<7)|(dst&127)
__global__ __launch_bounds__(256) void bucket_scatter(const int* __restrict__ ei,
                                                      const int* __restrict__ blockCounts,
                                                      unsigned int* __restrict__ bucketPacked) {
    __shared__ int cur[NB];
    for (int b = threadIdx.x; b < NB; b += 256)
        cur[b] = blockCounts[blockIdx.x * NB + b];
    __syncthreads();
    int base = blockIdx.x * EPB;
    int lim  = min(EPB, N_EDGES - base);
    for (int i = threadIdx.x; i < lim; i += 256) {
        int s = ei[base + i];
        int d = ei[N_EDGES + base + i];
        int pos = atomicAdd(&cur[d >> 7], 1);
        bucketPacked[pos] = ((unsigned int)s << 7) | (unsigned int)(d & 127);
    }
}

// fused: per-bucket degree count -> in-bucket scan -> rowptr -> local scatter.
__global__ __launch_bounds__(256) void node_scan_scatter(
    const unsigned int* __restrict__ bucketPacked, const int* __restrict__ bucketBase,
    int* __restrict__ rowptr, int* __restrict__ csr_src) {
    __shared__ int cnt[128];
    __shared__ int half0;
    __shared__ unsigned int stage[CAP];
    int tid = threadIdx.x;
    if (tid < 128) cnt[tid] = 0;
    __syncthreads();
    int beg = bucketBase[blockIdx.x], end = bucketBase[blockIdx.x + 1];
    int n = end - beg;
    for (int i = tid; i < n; i += 256) {
        unsigned int e = bucketPacked[beg + i];
        if (i < CAP) stage[i] = e;
        atomicAdd(&cnt[e & 127], 1);
    }
    __syncthreads();
    int lane = tid & 63;
    int v    = (tid < 128) ? cnt[tid] : 0;
    int incl = v;
#pragma unroll
    for (int off = 1; off < 64; off <<= 1) {
        int t = __shfl_up(incl, off, 64);
        if (lane >= off) incl += t;
    }
    if (tid == 63) half0 = incl;
    __syncthreads();
    int base  = beg + ((tid >= 64 && tid < 128) ? half0 : 0);
    int start = base + incl - v;
    int node  = blockIdx.x * 128 + tid;
    if (tid < 128) {
        if (node < N_NODES) rowptr[node] = start;
        cnt[tid] = start;   // becomes the scatter cursor
    }
    if (blockIdx.x == 0 && tid == 128) rowptr[N_NODES] = N_EDGES;
    __syncthreads();
    for (int i = tid; i < n; i += 256) {
        unsigned int e = (i < CAP) ? stage[i] : bucketPacked[beg + i];
        int pos = atomicAdd(&cnt[e & 127], 1);
        csr_src[pos] = (int)(e >> 7);
    }
}

// ==== gemm wrapper (layers 1,2) ==============================================
template <int K, bool F32IN>
__global__ __launch_bounds__(256) void gemm_dual_mfma(
    const void* __restrict__ Av,
    const unsigned short* __restrict__ pS,
    const unsigned short* __restrict__ pN,
    float* __restrict__ hs, unsigned char* __restrict__ hnq) {
    gemm_body<K, F32IN>(Av, pS, pN, hs, hnq, blockIdx.x);
}

// ==== fused gather-aggregate + update (+ optional MLP head) ==================
// Round-11 shape: 4 nodes per WAVE, 16 lanes per node (sn = tid>>4 node slot,
// r = lane&15 the 4B chunk of the 64B fp8 row). 12500 waves (~12/SIMD, 2x the
// latency hiding of round-10). Index loads are 2x dwordx4 per 8-edge batch
// (batch start aligned down to a multiple of 8; head/tail entries masked to
// the sentinel zero row at hnq[N_NODES] via one unsigned range-compare each).
// #pragma unroll 2 lets the scheduler overlap batch t+1's idx loads + gathers
// with batch t's converts. Grid covers exactly 50000 nodes (3125 x 16).
template <bool MLP>
__global__ __launch_bounds__(256) void agg_update(
    const int* __restrict__ rowptr, const int* __restrict__ csr_src,
    const unsigned char* __restrict__ hnq, const float* __restrict__ hs,
    unsigned short* __restrict__ hb_out,
    const float* __restrict__ mw1, const float* __restrict__ mb1,
    const float* __restrict__ mw2, const float* __restrict__ mb2,
    float* __restrict__ out) {
    __shared__ float sW1[MLP ? HID * 32 : 1];
    __shared__ float sW2[MLP ? 32 : 1];
    __shared__ float sB1[MLP ? 32 : 1];
    __shared__ float sH[MLP ? 16 * 68 : 1];   // 16 node slots, stride 68 (bank-spread)
    if (MLP) {
        for (int i = threadIdx.x; i < HID * 32; i += 256) sW1[i] = mw1[i];
        if (threadIdx.x < 32) { sW2[threadIdx.x] = mw2[threadIdx.x]; sB1[threadIdx.x] = mb1[threadIdx.x]; }
        __syncthreads();
    }
    int sn   = threadIdx.x >> 4;          // node slot within block, 0..15
    int r    = threadIdx.x & 15;          // 4B chunk of the 64B row
    int node = blockIdx.x * 16 + sn;      // grid = 3125 -> exactly N_NODES
    int beg = rowptr[node];
    int end = rowptr[node + 1];
    int deg = end - beg;
    int tbase = beg & ~7;                 // 32B-aligned batch start
    int nbat  = (end - tbase + 7) >> 3;
    const i32x4* ip = (const i32x4*)(csr_src + tbase);
    const unsigned char* hrow = hnq + r * 4;

    f32x2 acc2[2];
    acc2[0] = (f32x2){0.f, 0.f};
    acc2[1] = (f32x2){0.f, 0.f};
    int pr = tbase - beg;                 // relative position of batch start (<=0)

#pragma unroll 2
    for (int t = 0; t < nbat; ++t) {
        i32x4 a = ip[2 * t];
        i32x4 b = ip[2 * t + 1];
        int p0 = pr + 8 * t;
        int si[8];
#pragma unroll
        for (int u = 0; u < 4; ++u) {
            si[u]     = ((unsigned)(p0 + u)     < (unsigned)deg) ? a[u] : N_NODES;
            si[u + 4] = ((unsigned)(p0 + 4 + u) < (unsigned)deg) ? b[u] : N_NODES;
        }
        unsigned wv[8];
#pragma unroll
        for (int u = 0; u < 8; ++u)
            wv[u] = *(const unsigned*)(hrow + ((unsigned)si[u] << 6));
#pragma unroll
        for (int u = 0; u < 8; ++u) {
#if __has_builtin(__builtin_amdgcn_cvt_pk_f32_fp8)
            acc2[0] += __builtin_amdgcn_cvt_pk_f32_fp8((int)wv[u], false);
            acc2[1] += __builtin_amdgcn_cvt_pk_f32_fp8((int)wv[u], true);
#else
            acc2[0] += (f32x2){__builtin_amdgcn_cvt_f32_fp8((int)wv[u], 0),
                               __builtin_amdgcn_cvt_f32_fp8((int)wv[u], 1)};
            acc2[1] += (f32x2){__builtin_amdgcn_cvt_f32_fp8((int)wv[u], 2),
                               __builtin_amdgcn_cvt_f32_fp8((int)wv[u], 3)};
#endif
        }
    }

    float acc[4] = {acc2[0][0], acc2[0][1], acc2[1][0], acc2[1][1]};
    float invdeg = 1.0f / fmaxf((float)deg, 1.0f);
    f32x4 h = *(const f32x4*)(hs + (size_t)node * HID + r * 4);
    float v[4], ss = 0.f;
#pragma unroll
    for (int k = 0; k < 4; ++k) {
        v[k] = fmaxf(fmaf(acc[k], invdeg, h[k]), 0.f);
        ss += v[k] * v[k];
    }
    // reduce across the 16 r-lanes of this node (masks 1,2,4,8)
    ss += __shfl_xor(ss, 1, 64);
    ss += __shfl_xor(ss, 2, 64);
    ss += __shfl_xor(ss, 4, 64);
    ss += __shfl_xor(ss, 8, 64);
    float rs = 1.0f / (sqrtf(ss) + EPS);
    if (MLP) {
#pragma unroll
        for (int k = 0; k < 4; ++k) sH[sn * 68 + r * 4 + k] = v[k] * rs;
        __syncthreads();
        // per node: 16 threads x 2 columns of the 64x32 MLP
        int c0 = r * 2;
        float y0 = sB1[c0], y1 = sB1[c0 + 1];
        const float* hrow2 = &sH[sn * 68];
#pragma unroll 8
        for (int k = 0; k < HID; ++k) {
            float hv = hrow2[k];
            y0 = fmaf(hv, sW1[k * 32 + c0], y0);
            y1 = fmaf(hv, sW1[k * 32 + c0 + 1], y1);
        }
        float p = fmaxf(y0, 0.f) * sW2[c0] + fmaxf(y1, 0.f) * sW2[c0 + 1];
        p += __shfl_xor(p, 1, 64);
        p += __shfl_xor(p, 2, 64);
        p += __shfl_xor(p, 4, 64);
        p += __shfl_xor(p, 8, 64);
        if (r == 0) out[node] = 1.0f / (1.0f + __expf(-(p + mb2[0])));
    } else {
        // each lane owns 4 features -> 8B bf16 store
        bf16x4_t o;
#pragma unroll
        for (int k = 0; k < 4; ++k) o[k] = f2bf(v[k] * rs);
        *(bf16x4_t*)(hb_out + (size_t)node * HID + r * 4) = o;
    }
}

extern "C" void kernel_launch(void* const* d_in, const int* in_sizes, int n_in,
                              void* d_out, int out_size, void* d_ws, size_t ws_size,
                              hipStream_t stream) {
    const float* x   = (const float*)d_in[0];
    const int*   ei  = (const int*)d_in[1];
    const float* w0s = (const float*)d_in[2];
    const float* w0n = (const float*)d_in[3];
    const float* w1s = (const float*)d_in[4];
    const float* w1n = (const float*)d_in[5];
    const float* w2s = (const float*)d_in[6];
    const float* w2n = (const float*)d_in[7];
    const float* mw1 = (const float*)d_in[8];
    const float* mb1 = (const float*)d_in[9];
    const float* mw2 = (const float*)d_in[10];
    const float* mb2 = (const float*)d_in[11];
    float*       out = (float*)d_out;

    // ---- workspace layout (all sections 16B aligned) ----
    int* rowptr      = (int*)d_ws;               // 50432 (>= N+1)
    int* csr_src     = rowptr + 50432;           // 1.6M
    int* blockCounts = csr_src + N_EDGES;        // NBLK*NB = 152881 (pad 153600)
    int* bucketBase  = blockCounts + 153600;     // 512
    int* totals      = bucketBase + 512;         // 512
    unsigned int* bucketPacked = (unsigned int*)(totals + 512);   // 1.6M uint (6.4MB)
    const size_t NH = (size_t)N_NODES * HID;
    float*          hs  = (float*)(bucketPacked + N_EDGES);       // NH f32
    unsigned char*  hnq = (unsigned char*)(hs + NH);              // NH fp8 + 64B zero row
    unsigned short* hb  = (unsigned short*)(hnq + NH + 64);       // NH bf16
    unsigned short* p0S = hb + NH;               // 128*64
    unsigned short* p0N = p0S + IN_DIM * HID;
    unsigned short* p1S = p0N + IN_DIM * HID;    // 64*64
    unsigned short* p1N = p1S + HID * HID;
    unsigned short* p2S = p1N + HID * HID;
    unsigned short* p2N = p2S + HID * HID;
    // total ~36 MB

    const int nodeGrid = N_NODES / 16;           // 3125 blocks: 16 nodes/block, 4 waves
    const int gemmGrid = (N_NODES / 16 + 3) / 4; // 782

    // ---- CSR build + weight pack + layer-0 GEMM (packed into idle dispatches) ----
    bucket_count_pack<<<NBLK + 8, 256, 0, stream>>>(
        ei, blockCounts, w0s, w0n, w1s, w1n, w2s, w2n,
        p0S, p0N, p1S, p1N, p2S, p2N, hnq);
    col_sum_gemm0<<<NB + gemmGrid, 256, 0, stream>>>(
        blockCounts, totals, x, p0S, p0N, hs, hnq);
    col_fix_base<<<NB, 256, 0, stream>>>(blockCounts, totals, bucketBase);
    bucket_scatter<<<NBLK, 256, 0, stream>>>(ei, blockCounts, bucketPacked);
    node_scan_scatter<<<NB, 256, 0, stream>>>(bucketPacked, bucketBase, rowptr, csr_src);

    // ---- layer 0 aggregate (gemm L0 already done in col_sum dispatch) ----
    agg_update<false><<<nodeGrid, 256, 0, stream>>>(
        rowptr, csr_src, hnq, hs, hb, nullptr, nullptr, nullptr, nullptr, nullptr);

    // ---- layer 1 ----
    gemm_dual_mfma<HID, false><<<gemmGrid, 256, 0, stream>>>(hb, p1S, p1N, hs, hnq);
    agg_update<false><<<nodeGrid, 256, 0, stream>>>(
        rowptr, csr_src, hnq, hs, hb, nullptr, nullptr, nullptr, nullptr, nullptr);

    // ---- layer 2 (+ fused MLP head) ----
    gemm_dual_mfma<HID, false><<<gemmGrid, 256, 0, stream>>>(hb, p2S, p2N, hs, hnq);
    agg_update<true><<<nodeGrid, 256, 0, stream>>>(
        rowptr, csr_src, hnq, hs, nullptr, mw1, mb1, mw2, mb2, out);
}

// Round 6
// 204.080 us; speedup vs baseline: 1.0954x; 1.0954x over previous
//
#include <hip/hip_runtime.h>
#include <hip/hip_bf16.h>
#include <math.h>

#define N_NODES 50000
#define N_EDGES 1600000
#define IN_DIM  128
#define HID     64
#define EPB     4096   // edges per sort block
#define NBLK    391    // ceil(N_EDGES / EPB)
#define NB      391    // ceil(N_NODES / 128) buckets of 128 nodes
#define CAP     8192   // LDS staging capacity (edges/bucket; mean 4092)
#define PBKT    8192   // padded per-bucket arena in csr_pad (max ~5300 used)
static constexpr float EPS = 1e-6f;

typedef __attribute__((ext_vector_type(8))) short          short8;   // 8 bf16
typedef __attribute__((ext_vector_type(8))) unsigned short ushort8;
typedef __attribute__((ext_vector_type(4))) unsigned short bf16x4_t;
typedef __attribute__((ext_vector_type(4))) int            i32x4;
typedef __attribute__((ext_vector_type(4))) float          f32x4;
typedef __attribute__((ext_vector_type(2))) float          f32x2;

__device__ __forceinline__ unsigned short f2bf(float f) {   // round-nearest-even
    union { float f; unsigned int i; } c; c.f = f;
    unsigned int r = c.i + 0x7FFFu + ((c.i >> 16) & 1u);
    return (unsigned short)(r >> 16);
}
__device__ __forceinline__ unsigned char f2fp8(float f) {   // OCP e4m3, HW cvt
    int p = __builtin_amdgcn_cvt_pk_fp8_f32(f, f, 0, false);
    return (unsigned char)(p & 0xff);
}

// ==== weight packing =========================================================

template <int K>
__device__ __forceinline__ void pack_body(const float* __restrict__ wS,
                                          const float* __restrict__ wN,
                                          unsigned short* __restrict__ pS,
                                          unsigned short* __restrict__ pN, int blk) {
    constexpr int NSLOT = (K / 32) * 4 * 64;
    int slot = blk * 256 + (int)threadIdx.x;
    if (slot >= NSLOT) return;
    int lane = slot & 63;
    int ct   = slot >> 6;
    int t    = ct & 3;
    int c    = ct >> 2;
    int m    = lane & 15;
    int quad = lane >> 4;
    int col  = t * 16 + m;
#pragma unroll
    for (int j = 0; j < 8; ++j) {
        int k = c * 32 + quad * 8 + j;
        pS[slot * 8 + j] = f2bf(wS[k * 64 + col]);
        pN[slot * 8 + j] = f2bf(wN[k * 64 + col]);
    }
}

// ==== CSR build: binned counting sort ========================================

// blocks 0..NBLK-1: per-block bucket histogram; blocks NBLK..NBLK+7: weight pack
// (also zeroes the sentinel rows at hnqA[N_NODES] / hnqB[N_NODES])
__global__ __launch_bounds__(256) void bucket_count_pack(
    const int* __restrict__ ei, int* __restrict__ blockCounts,
    const float* __restrict__ w0s, const float* __restrict__ w0n,
    const float* __restrict__ w1s, const float* __restrict__ w1n,
    const float* __restrict__ w2s, const float* __restrict__ w2n,
    unsigned short* __restrict__ p0S, unsigned short* __restrict__ p0N,
    unsigned short* __restrict__ p1S, unsigned short* __restrict__ p1N,
    unsigned short* __restrict__ p2S, unsigned short* __restrict__ p2N,
    unsigned char* __restrict__ hnqA, unsigned char* __restrict__ hnqB) {
    if (blockIdx.x >= NBLK) {
        int blk = blockIdx.x - NBLK;
        if (blk == 7) {
            if (threadIdx.x >= 128 && threadIdx.x < 144)
                ((unsigned int*)(hnqA + (size_t)N_NODES * HID))[threadIdx.x - 128] = 0u;
            if (threadIdx.x >= 144 && threadIdx.x < 160)
                ((unsigned int*)(hnqB + (size_t)N_NODES * HID))[threadIdx.x - 144] = 0u;
        }
        if (blk < 4)      pack_body<IN_DIM>(w0s, w0n, p0S, p0N, blk);
        else if (blk < 6) pack_body<HID>(w1s, w1n, p1S, p1N, blk - 4);
        else              pack_body<HID>(w2s, w2n, p2S, p2N, blk - 6);
        return;
    }
    __shared__ int hist[NB];
    for (int i = threadIdx.x; i < NB; i += 256) hist[i] = 0;
    __syncthreads();
    int base = blockIdx.x * EPB;
    int lim  = min(EPB, N_EDGES - base);
    for (int i = threadIdx.x; i < lim; i += 256)
        atomicAdd(&hist[ei[N_EDGES + base + i] >> 7], 1);
    __syncthreads();
    for (int b = threadIdx.x; b < NB; b += 256)
        blockCounts[blockIdx.x * NB + b] = hist[b];
}

// ==== dual GEMM body (layer 0 only) ==========================================
// hs = A@wS (fp32 out), hn = A@wN (fp8 e4m3 out)
template <int K, bool F32IN>
__device__ __forceinline__ void gemm_body(
    const void* __restrict__ Av,
    const unsigned short* __restrict__ pS,
    const unsigned short* __restrict__ pN,
    float* __restrict__ hs, unsigned char* __restrict__ hnq, int blk) {
    constexpr int NC = K / 32;
    int lane = threadIdx.x & 63;
    int wv   = threadIdx.x >> 6;
    int tile = blk * 4 + wv;
    if (tile >= N_NODES / 16) return;
    int m    = lane & 15;
    int quad = lane >> 4;

    const short8* pSf = (const short8*)pS;
    const short8* pNf = (const short8*)pN;

    f32x4 accS[4], accN[4];
#pragma unroll
    for (int t = 0; t < 4; ++t) {
        accS[t] = (f32x4){0.f, 0.f, 0.f, 0.f};
        accN[t] = (f32x4){0.f, 0.f, 0.f, 0.f};
    }
#pragma unroll
    for (int c = 0; c < NC; ++c) {
        short8 a;
        if constexpr (F32IN) {
            const float* Af = (const float*)Av + ((size_t)tile * 16 + m) * K + quad * 8 + c * 32;
            f32x4 a0 = *(const f32x4*)Af;
            f32x4 a1 = *(const f32x4*)(Af + 4);
#pragma unroll
            for (int k = 0; k < 4; ++k) a[k]     = (short)f2bf(a0[k]);
#pragma unroll
            for (int k = 0; k < 4; ++k) a[k + 4] = (short)f2bf(a1[k]);
        } else {
            const short8* Af = (const short8*)((const unsigned short*)Av +
                               ((size_t)tile * 16 + m) * K + quad * 8);
            a = Af[c * 4];
        }
#pragma unroll
        for (int t = 0; t < 4; ++t) {
            short8 bs = pSf[(c * 4 + t) * 64 + lane];
            short8 bn = pNf[(c * 4 + t) * 64 + lane];
            accS[t] = __builtin_amdgcn_mfma_f32_16x16x32_bf16(a, bs, accS[t], 0, 0, 0);
            accN[t] = __builtin_amdgcn_mfma_f32_16x16x32_bf16(a, bn, accN[t], 0, 0, 0);
        }
    }
    int row0 = tile * 16 + quad * 4;
#pragma unroll
    for (int t = 0; t < 4; ++t) {
#pragma unroll
        for (int r = 0; r < 4; ++r) {
            size_t o = (size_t)(row0 + r) * HID + t * 16 + m;
            hs[o]  = accS[t][r];
            hnq[o] = f2fp8(accN[t][r]);
        }
    }
}

// blocks 0..NB-1: col_sum; blocks NB.. : layer-0 GEMM (independent work overlap)
__global__ __launch_bounds__(256) void col_sum_gemm0(
    const int* __restrict__ blockCounts, int* __restrict__ totals,
    const float* __restrict__ x,
    const unsigned short* __restrict__ p0S, const unsigned short* __restrict__ p0N,
    float* __restrict__ hs, unsigned char* __restrict__ hnq) {
    if (blockIdx.x >= NB) {
        gemm_body<IN_DIM, true>(x, p0S, p0N, hs, hnq, blockIdx.x - NB);
        return;
    }
    __shared__ int ws[4];
    int b = blockIdx.x;
    int s = 0;
    for (int i = threadIdx.x; i < NBLK; i += 256) s += blockCounts[i * NB + b];
#pragma unroll
    for (int off = 32; off >= 1; off >>= 1) s += __shfl_xor(s, off, 64);
    if ((threadIdx.x & 63) == 0) ws[threadIdx.x >> 6] = s;
    __syncthreads();
    if (threadIdx.x == 0) totals[b] = ws[0] + ws[1] + ws[2] + ws[3];
}

// col_fix + integrated base scan
__global__ __launch_bounds__(256) void col_fix_base(int* __restrict__ blockCounts,
                                                    const int* __restrict__ totals,
                                                    int* __restrict__ bucketBase) {
    __shared__ int vals[NBLK];
    __shared__ int sbase;
    int b = blockIdx.x;
    for (int i = threadIdx.x; i < NBLK; i += 256) vals[i] = blockCounts[i * NB + b];
    if (threadIdx.x < 64) {   // wave 0: base_b = sum totals[0..b)
        int lane = threadIdx.x;
        int s = 0;
        for (int i = lane; i < b; i += 64) s += totals[i];
#pragma unroll
        for (int off = 32; off >= 1; off >>= 1) s += __shfl_xor(s, off, 64);
        if (lane == 0) {
            sbase = s;
            bucketBase[b] = s;
            if (b == NB - 1) bucketBase[NB] = s + totals[b];   // == N_EDGES
        }
    }
    __syncthreads();
    if (threadIdx.x < 64) {
        int lane  = threadIdx.x;
        int carry = sbase;
        for (int base = 0; base < NBLK; base += 64) {
            int i = base + lane;
            int v = (i < NBLK) ? vals[i] : 0;
            int incl = v;
#pragma unroll
            for (int off = 1; off < 64; off <<= 1) {
                int t = __shfl_up(incl, off, 64);
                if (lane >= off) incl += t;
            }
            if (i < NBLK) vals[i] = carry + incl - v;
            carry += __shfl(incl, 63, 64);
        }
    }
    __syncthreads();
    for (int i = threadIdx.x; i < NBLK; i += 256) blockCounts[i * NB + b] = vals[i];
}

// scatter edges into bucket-sorted order, packed (src<<7)|(dst&127)
__global__ __launch_bounds__(256) void bucket_scatter(const int* __restrict__ ei,
                                                      const int* __restrict__ blockCounts,
                                                      unsigned int* __restrict__ bucketPacked) {
    __shared__ int cur[NB];
    for (int b = threadIdx.x; b < NB; b += 256)
        cur[b] = blockCounts[blockIdx.x * NB + b];
    __syncthreads();
    int base = blockIdx.x * EPB;
    int lim  = min(EPB, N_EDGES - base);
    for (int i = threadIdx.x; i < lim; i += 256) {
        int s = ei[base + i];
        int d = ei[N_EDGES + base + i];
        int pos = atomicAdd(&cur[d >> 7], 1);
        bucketPacked[pos] = ((unsigned int)s << 7) | (unsigned int)(d & 127);
    }
}

// fused: per-bucket degree count -> PADDED in-bucket scan -> pbeg/rdeg ->
// sentinel fill -> local scatter into the padded per-bucket arena csr_pad.
// Each node's segment is padded to a multiple of 8 with sentinel N_NODES so
// the gather loop needs no per-edge tail masking.
__global__ __launch_bounds__(256) void node_scan_scatter_pad(
    const unsigned int* __restrict__ bucketPacked, const int* __restrict__ bucketBase,
    int* __restrict__ pbeg, int* __restrict__ rdeg, int* __restrict__ csr_pad) {
    __shared__ int cnt[128];
    __shared__ int half0;
    __shared__ unsigned int stage[CAP];
    int tid = threadIdx.x;
    if (tid < 128) cnt[tid] = 0;
    __syncthreads();
    int beg = bucketBase[blockIdx.x], end = bucketBase[blockIdx.x + 1];
    int n = end - beg;
    for (int i = tid; i < n; i += 256) {
        unsigned int e = bucketPacked[beg + i];
        if (i < CAP) stage[i] = e;
        atomicAdd(&cnt[e & 127], 1);
    }
    __syncthreads();
    int lane = tid & 63;
    int v    = (tid < 128) ? cnt[tid] : 0;   // raw degree of node tid
    int vp   = (v + 7) & ~7;                 // padded degree
    int incl = vp;
#pragma unroll
    for (int off = 1; off < 64; off <<= 1) {
        int t = __shfl_up(incl, off, 64);
        if (lane >= off) incl += t;
    }
    if (tid == 63) half0 = incl;
    __syncthreads();
    int start = blockIdx.x * PBKT + ((tid >= 64 && tid < 128) ? half0 : 0) + incl - vp;
    int node  = blockIdx.x * 128 + tid;
    if (tid < 128 && node < N_NODES) {
        pbeg[node] = start;
        rdeg[node] = v;
        for (int j = v; j < vp; ++j) csr_pad[start + j] = N_NODES;   // sentinels
        cnt[tid] = start;   // becomes the scatter cursor
    }
    __syncthreads();
    for (int i = tid; i < n; i += 256) {
        unsigned int e = (i < CAP) ? stage[i] : bucketPacked[beg + i];
        int pos = atomicAdd(&cnt[e & 127], 1);
        csr_pad[pos] = (int)(e >> 7);
    }
}

// ==== fused gather-aggregate + update + NEXT-LAYER dual GEMM (or MLP head) ===
// 4 nodes per wave, 16 lanes per node (sn = tid>>4, r = lane&15 -> 4B chunk).
// Maskless main loop (padded CSR): per edge = addr-fma + load + 2 cvt + 2 add.
// !MLP: the block's 16 nodes form one GEMM tile. Normalized bf16 rows staged
// in LDS (stride 80 shorts, bank-spread), then the 4 waves each compute one
// (matrix, t-pair) quarter of the dual MFMA GEMM -> next layer's hs2/hnq2.
// Eliminates the standalone gemm dispatches and the hb tensor entirely.
template <bool MLP>
__global__ __launch_bounds__(256) void agg_update(
    const int* __restrict__ pbeg, const int* __restrict__ rdeg,
    const int* __restrict__ csr_pad,
    const unsigned char* __restrict__ hnq, const float* __restrict__ hs,
    const unsigned short* __restrict__ pS, const unsigned short* __restrict__ pN,
    float* __restrict__ hs2, unsigned char* __restrict__ hnq2,
    const float* __restrict__ mw1, const float* __restrict__ mb1,
    const float* __restrict__ mw2, const float* __restrict__ mb2,
    float* __restrict__ out) {
    __shared__ unsigned short sA[MLP ? 1 : 16 * 80];   // 16 nodes x 64 bf16, stride 80
    __shared__ float sW1[MLP ? HID * 32 : 1];
    __shared__ float sW2[MLP ? 32 : 1];
    __shared__ float sB1[MLP ? 32 : 1];
    __shared__ float sH[MLP ? 16 * 68 : 1];
    if (MLP) {
        for (int i = threadIdx.x; i < HID * 32; i += 256) sW1[i] = mw1[i];
        if (threadIdx.x < 32) { sW2[threadIdx.x] = mw2[threadIdx.x]; sB1[threadIdx.x] = mb1[threadIdx.x]; }
        __syncthreads();
    }
    int sn   = threadIdx.x >> 4;          // node slot within block, 0..15
    int r    = threadIdx.x & 15;          // 4B chunk of the 64B row
    int node = blockIdx.x * 16 + sn;      // grid = 3125 -> exactly N_NODES
    int beg  = pbeg[node];
    int dg   = rdeg[node];
    int nbat = (dg + 7) >> 3;
    const i32x4* ip = (const i32x4*)(csr_pad + beg);
    unsigned r4 = (unsigned)(r * 4);

    f32x2 acc2[2];
    acc2[0] = (f32x2){0.f, 0.f};
    acc2[1] = (f32x2){0.f, 0.f};

#pragma unroll 2
    for (int t = 0; t < nbat; ++t) {
        i32x4 a = ip[2 * t];
        i32x4 b = ip[2 * t + 1];
        unsigned wv[8];
#pragma unroll
        for (int u = 0; u < 4; ++u)
            wv[u]     = *(const unsigned*)(hnq + (((unsigned)a[u] << 6) + r4));
#pragma unroll
        for (int u = 0; u < 4; ++u)
            wv[u + 4] = *(const unsigned*)(hnq + (((unsigned)b[u] << 6) + r4));
#pragma unroll
        for (int u = 0; u < 8; ++u) {
#if __has_builtin(__builtin_amdgcn_cvt_pk_f32_fp8)
            acc2[0] += __builtin_amdgcn_cvt_pk_f32_fp8((int)wv[u], false);
            acc2[1] += __builtin_amdgcn_cvt_pk_f32_fp8((int)wv[u], true);
#else
            acc2[0] += (f32x2){__builtin_amdgcn_cvt_f32_fp8((int)wv[u], 0),
                               __builtin_amdgcn_cvt_f32_fp8((int)wv[u], 1)};
            acc2[1] += (f32x2){__builtin_amdgcn_cvt_f32_fp8((int)wv[u], 2),
                               __builtin_amdgcn_cvt_f32_fp8((int)wv[u], 3)};
#endif
        }
    }

    float acc[4] = {acc2[0][0], acc2[0][1], acc2[1][0], acc2[1][1]};
    float invdeg = 1.0f / fmaxf((float)dg, 1.0f);
    f32x4 h = *(const f32x4*)(hs + (size_t)node * HID + r * 4);
    float v[4], ss = 0.f;
#pragma unroll
    for (int k = 0; k < 4; ++k) {
        v[k] = fmaxf(fmaf(acc[k], invdeg, h[k]), 0.f);
        ss += v[k] * v[k];
    }
    // reduce across the 16 r-lanes of this node (masks 1,2,4,8)
    ss += __shfl_xor(ss, 1, 64);
    ss += __shfl_xor(ss, 2, 64);
    ss += __shfl_xor(ss, 4, 64);
    ss += __shfl_xor(ss, 8, 64);
    float rs = 1.0f / (sqrtf(ss) + EPS);

    if constexpr (!MLP) {
        // stage normalized row as bf16 into LDS (A-operand of next GEMM)
        unsigned short* ap = &sA[sn * 80 + r * 4];
#pragma unroll
        for (int k = 0; k < 4; ++k) ap[k] = f2bf(v[k] * rs);
        __syncthreads();
        // dual GEMM: wave wv_ covers (mat = wv_>>1, t-pair = (wv_&1)*2)
        int lane = threadIdx.x & 63;
        int wv_  = threadIdx.x >> 6;
        int m    = lane & 15;
        int quad = lane >> 4;
        const short8* pB = (const short8*)((wv_ < 2) ? pS : pN);
        int t0 = (wv_ & 1) * 2;
        f32x4 gacc[2];
        gacc[0] = (f32x4){0.f, 0.f, 0.f, 0.f};
        gacc[1] = (f32x4){0.f, 0.f, 0.f, 0.f};
#pragma unroll
        for (int c = 0; c < 2; ++c) {
            short8 a = *(const short8*)&sA[m * 80 + quad * 8 + c * 32];
#pragma unroll
            for (int tt = 0; tt < 2; ++tt) {
                short8 b = pB[(c * 4 + t0 + tt) * 64 + lane];
                gacc[tt] = __builtin_amdgcn_mfma_f32_16x16x32_bf16(a, b, gacc[tt], 0, 0, 0);
            }
        }
        int row0 = blockIdx.x * 16 + quad * 4;
#pragma unroll
        for (int tt = 0; tt < 2; ++tt) {
            int col = (t0 + tt) * 16 + m;
#pragma unroll
            for (int rr = 0; rr < 4; ++rr) {
                size_t o = (size_t)(row0 + rr) * HID + col;
                if (wv_ < 2) hs2[o]  = gacc[tt][rr];
                else         hnq2[o] = f2fp8(gacc[tt][rr]);
            }
        }
    } else {
#pragma unroll
        for (int k = 0; k < 4; ++k) sH[sn * 68 + r * 4 + k] = v[k] * rs;
        __syncthreads();
        // per node: 16 threads x 2 columns of the 64x32 MLP
        int c0 = r * 2;
        float y0 = sB1[c0], y1 = sB1[c0 + 1];
        const float* hrow2 = &sH[sn * 68];
#pragma unroll 8
        for (int k = 0; k < HID; ++k) {
            float hv = hrow2[k];
            y0 = fmaf(hv, sW1[k * 32 + c0], y0);
            y1 = fmaf(hv, sW1[k * 32 + c0 + 1], y1);
        }
        float p = fmaxf(y0, 0.f) * sW2[c0] + fmaxf(y1, 0.f) * sW2[c0 + 1];
        p += __shfl_xor(p, 1, 64);
        p += __shfl_xor(p, 2, 64);
        p += __shfl_xor(p, 4, 64);
        p += __shfl_xor(p, 8, 64);
        if (r == 0) out[node] = 1.0f / (1.0f + __expf(-(p + mb2[0])));
    }
}

extern "C" void kernel_launch(void* const* d_in, const int* in_sizes, int n_in,
                              void* d_out, int out_size, void* d_ws, size_t ws_size,
                              hipStream_t stream) {
    const float* x   = (const float*)d_in[0];
    const int*   ei  = (const int*)d_in[1];
    const float* w0s = (const float*)d_in[2];
    const float* w0n = (const float*)d_in[3];
    const float* w1s = (const float*)d_in[4];
    const float* w1n = (const float*)d_in[5];
    const float* w2s = (const float*)d_in[6];
    const float* w2n = (const float*)d_in[7];
    const float* mw1 = (const float*)d_in[8];
    const float* mb1 = (const float*)d_in[9];
    const float* mw2 = (const float*)d_in[10];
    const float* mb2 = (const float*)d_in[11];
    float*       out = (float*)d_out;

    // ---- workspace layout (all sections 16B aligned) ----
    int* pbeg        = (int*)d_ws;               // 50048
    int* rdeg        = pbeg + 50048;             // 50048
    int* blockCounts = rdeg + 50048;             // NBLK*NB = 152881 (pad 153600)
    int* bucketBase  = blockCounts + 153600;     // 512
    int* totals      = bucketBase + 512;         // 512
    unsigned int* bucketPacked = (unsigned int*)(totals + 512);   // 1.6M uint
    int* csr_pad     = (int*)(bucketPacked + N_EDGES);            // NB*PBKT = 3,203,072
    const size_t NH = (size_t)N_NODES * HID;
    float*          hsA  = (float*)(csr_pad + NB * PBKT);         // NH f32
    unsigned char*  hnqA = (unsigned char*)(hsA + NH);            // NH fp8 + 64B zero row
    float*          hsB  = (float*)(hnqA + NH + 64);              // NH f32
    unsigned char*  hnqB = (unsigned char*)(hsB + NH);            // NH fp8 + 64B zero row
    unsigned short* p0S = (unsigned short*)(hnqB + NH + 64);      // 128*64
    unsigned short* p0N = p0S + IN_DIM * HID;
    unsigned short* p1S = p0N + IN_DIM * HID;    // 64*64
    unsigned short* p1N = p1S + HID * HID;
    unsigned short* p2S = p1N + HID * HID;
    unsigned short* p2N = p2S + HID * HID;
    // total ~55 MB

    const int nodeGrid = N_NODES / 16;           // 3125 blocks: 16 nodes/block, 4 waves
    const int gemmGrid = (N_NODES / 16 + 3) / 4; // 782 (layer-0 GEMM only)

    // ---- CSR build + weight pack + layer-0 GEMM (packed into idle dispatches) ----
    bucket_count_pack<<<NBLK + 8, 256, 0, stream>>>(
        ei, blockCounts, w0s, w0n, w1s, w1n, w2s, w2n,
        p0S, p0N, p1S, p1N, p2S, p2N, hnqA, hnqB);
    col_sum_gemm0<<<NB + gemmGrid, 256, 0, stream>>>(
        blockCounts, totals, x, p0S, p0N, hsA, hnqA);
    col_fix_base<<<NB, 256, 0, stream>>>(blockCounts, totals, bucketBase);
    bucket_scatter<<<NBLK, 256, 0, stream>>>(ei, blockCounts, bucketPacked);
    node_scan_scatter_pad<<<NB, 256, 0, stream>>>(bucketPacked, bucketBase,
                                                  pbeg, rdeg, csr_pad);

    // ---- layer 0 aggregate + fused layer-1 GEMM ----
    agg_update<false><<<nodeGrid, 256, 0, stream>>>(
        pbeg, rdeg, csr_pad, hnqA, hsA, p1S, p1N, hsB, hnqB,
        nullptr, nullptr, nullptr, nullptr, nullptr);

    // ---- layer 1 aggregate + fused layer-2 GEMM ----
    agg_update<false><<<nodeGrid, 256, 0, stream>>>(
        pbeg, rdeg, csr_pad, hnqB, hsB, p2S, p2N, hsA, hnqA,
        nullptr, nullptr, nullptr, nullptr, nullptr);

    // ---- layer 2 aggregate + fused MLP head ----
    agg_update<true><<<nodeGrid, 256, 0, stream>>>(
        pbeg, rdeg, csr_pad, hnqA, hsA, nullptr, nullptr, nullptr, nullptr,
        mw1, mb1, mw2, mb2, out);
}